// Round 1
// baseline (419.434 us; speedup 1.0000x reference)
//
#include <hip/hip_runtime.h>
#include <hip/hip_bf16.h>

// LigandCrossAttention fused bf16-MFMA implementation for gfx950.
// B=16, S=2048, A=128, D_MODEL=512, H=8, Dh=64.

typedef __attribute__((ext_vector_type(8))) short short8;  // 8 x bf16 bits
typedef __attribute__((ext_vector_type(4))) float f32x4;

#define MFMA16(a, b, c) __builtin_amdgcn_mfma_f32_16x16x32_bf16((a), (b), (c), 0, 0, 0)
// XOR swizzle of within-row byte offset; breaks the 16-way bank conflict for
// row-major LDS tiles with power-of-2 row strides (Guide §6 G4).
#define SWZ(row, bo) ((bo) ^ (((row) & 7) << 4))

__device__ __forceinline__ short f2bf(float f) {  // fp32 -> bf16 bits, RNE
  unsigned int u = __float_as_uint(f);
  u += 0x7FFFu + ((u >> 16) & 1u);
  return (short)(u >> 16);
}

// ---------------------------------------------------------------------------
// Kernel 1: transpose fp32 [512][512] weights -> bf16 [n][k] (4 weights).
// ---------------------------------------------------------------------------
__global__ __launch_bounds__(256)
void wtrans_kernel(const float* __restrict__ Wq, const float* __restrict__ Wk,
                   const float* __restrict__ Wv, const float* __restrict__ Wo,
                   unsigned short* __restrict__ dst) {
  __shared__ float t[64][65];
  const int wsel = blockIdx.z;
  const float* src = (wsel == 0) ? Wq : (wsel == 1) ? Wk : (wsel == 2) ? Wv : Wo;
  unsigned short* d = dst + (size_t)wsel * 512 * 512;
  const int k0 = blockIdx.x * 64, n0 = blockIdx.y * 64;
  const int c = threadIdx.x & 63, r4 = threadIdx.x >> 6;
#pragma unroll
  for (int i = 0; i < 16; i++) {
    int row = i * 4 + r4;
    t[row][c] = src[(size_t)(k0 + row) * 512 + n0 + c];
  }
  __syncthreads();
#pragma unroll
  for (int i = 0; i < 16; i++) {
    int row = i * 4 + r4;
    d[(size_t)(n0 + row) * 512 + k0 + c] = (unsigned short)f2bf(t[c][row]);
  }
}

// ---------------------------------------------------------------------------
// Kernel 2: bav[b][a][h] = mask ? atom_emb[type][h] + bd[h] : -1e30
// ---------------------------------------------------------------------------
__global__ __launch_bounds__(256)
void bav_kernel(const int* __restrict__ types, const int* __restrict__ mask,
                const float* __restrict__ bd, const float* __restrict__ aemb,
                float* __restrict__ bav) {
  int t = blockIdx.x * 256 + threadIdx.x;  // 0..2047 = b*128+a
  int msk = mask[t];
  int tp = types[t];
#pragma unroll
  for (int h = 0; h < 8; h++)
    bav[(size_t)t * 8 + h] = msk ? (aemb[tp * 8 + h] + bd[h]) : -1e30f;
}

// ---------------------------------------------------------------------------
// Kernel 3: K/V projection. grid=(2 [k|v], 16 [b]), 512 thr.
// K -> kbuf[b][h][a][d] bf16 ; V -> vtbuf[b][h][d][a] bf16.
// ---------------------------------------------------------------------------
__global__ __launch_bounds__(512)
void kvproj_kernel(const float* __restrict__ ligand,
                   const unsigned short* __restrict__ WkT,
                   const unsigned short* __restrict__ WvT,
                   const float* __restrict__ bk, const float* __restrict__ bv,
                   unsigned short* __restrict__ kbuf,
                   unsigned short* __restrict__ vtbuf) {
  __shared__ short st[128 * 64];
  char* sb = (char*)st;
  const int kv = blockIdx.x, b = blockIdx.y;
  const unsigned short* WT = kv ? WvT : WkT;
  const float* bias = kv ? bv : bk;
  const int tid = threadIdx.x, lane = tid & 63, w = tid >> 6;
  const int c = lane & 15, g = lane >> 4;
  const f32x4 fz = {0.f, 0.f, 0.f, 0.f};
  f32x4 acc[8][4];
#pragma unroll
  for (int i = 0; i < 8; i++)
#pragma unroll
    for (int j = 0; j < 4; j++) acc[i][j] = fz;
  const int srow = tid >> 2, sq = tid & 3;
  for (int kb = 0; kb < 8; kb++) {
    const float* src = ligand + ((size_t)(b * 128 + srow) * 512 + kb * 64 + sq * 16);
    float4 x0 = ((const float4*)src)[0];
    float4 x1 = ((const float4*)src)[1];
    float4 x2 = ((const float4*)src)[2];
    float4 x3 = ((const float4*)src)[3];
    short8 v0, v1;
    v0[0] = f2bf(x0.x); v0[1] = f2bf(x0.y); v0[2] = f2bf(x0.z); v0[3] = f2bf(x0.w);
    v0[4] = f2bf(x1.x); v0[5] = f2bf(x1.y); v0[6] = f2bf(x1.z); v0[7] = f2bf(x1.w);
    v1[0] = f2bf(x2.x); v1[1] = f2bf(x2.y); v1[2] = f2bf(x2.z); v1[3] = f2bf(x2.w);
    v1[4] = f2bf(x3.x); v1[5] = f2bf(x3.y); v1[6] = f2bf(x3.z); v1[7] = f2bf(x3.w);
    *(short8*)(sb + srow * 128 + SWZ(srow, sq * 32)) = v0;
    *(short8*)(sb + srow * 128 + SWZ(srow, sq * 32 + 16)) = v1;
    __syncthreads();
#pragma unroll
    for (int kk = 0; kk < 64; kk += 32) {
      short8 af[8];
#pragma unroll
      for (int mt = 0; mt < 8; mt++) {
        int row = mt * 16 + c;
        af[mt] = *(const short8*)(sb + row * 128 + SWZ(row, kk * 2 + g * 16));
      }
#pragma unroll
      for (int nt = 0; nt < 4; nt++) {
        short8 bf = *(const short8*)(WT + (size_t)(w * 64 + nt * 16 + c) * 512 +
                                     kb * 64 + kk + g * 8);
#pragma unroll
        for (int mt = 0; mt < 8; mt++)
          acc[mt][nt] = MFMA16(af[mt], bf, acc[mt][nt]);
      }
    }
    __syncthreads();
  }
#pragma unroll
  for (int nt = 0; nt < 4; nt++) {
    int col = w * 64 + nt * 16 + c;
    float bs = bias[col];
    int h = col >> 6, dd = col & 63;
#pragma unroll
    for (int mt = 0; mt < 8; mt++)
#pragma unroll
      for (int r = 0; r < 4; r++) {
        int a = mt * 16 + g * 4 + r;  // D-layout: row = 4*(lane>>4)+reg (m89)
        unsigned short us = (unsigned short)f2bf(acc[mt][nt][r] + bs);
        if (!kv) kbuf[((size_t)(b * 8 + h) * 128 + a) * 64 + dd] = us;
        else     vtbuf[((size_t)(b * 8 + h) * 64 + dd) * 128 + a] = us;
      }
  }
}

// ---------------------------------------------------------------------------
// Kernel 4: fused Q-proj + attention + O-proj. grid=(32 s-tiles, 16 b), 512 thr.
// ---------------------------------------------------------------------------
__global__ __launch_bounds__(512)
void fused_kernel(const float* __restrict__ protein, const float* __restrict__ pcoord,
                  const float* __restrict__ lcoord, const float* __restrict__ Wdp,
                  const float* __restrict__ bq, const float* __restrict__ bo,
                  const unsigned short* __restrict__ WqT,
                  const unsigned short* __restrict__ WoT,
                  const unsigned short* __restrict__ kbuf,
                  const unsigned short* __restrict__ vtbuf,
                  const float* __restrict__ bav, float* __restrict__ out) {
  __shared__ short qs[64 * 512];        // q tile, bf16, swizzled          64 KB
  __shared__ short aos[64 * 512];       // attn-out tile, bf16, swizzled   64 KB
  __shared__ short scratch[64 * 128];   // union: A-stage (8KB) / P (16KB) 16 KB
  __shared__ float pc[64][4];
  __shared__ float lc[128][4];
  __shared__ float red[64][8];
  __shared__ float rmaxl[64];
  __shared__ float rinvl[64];

  char* qb = (char*)qs;
  char* aob = (char*)aos;
  char* ub = (char*)scratch;
  const int b = blockIdx.y, s0 = blockIdx.x * 64;
  const int tid = threadIdx.x, lane = tid & 63, w = tid >> 6;
  const int c = lane & 15, g = lane >> 4;
  const f32x4 fz = {0.f, 0.f, 0.f, 0.f};

  if (tid < 64) {
    const float* p3 = pcoord + (size_t)(b * 2048 + s0 + tid) * 3;
    pc[tid][0] = p3[0]; pc[tid][1] = p3[1]; pc[tid][2] = p3[2];
  } else if (tid < 192) {
    int a = tid - 64;
    const float* l3 = lcoord + (size_t)(b * 128 + a) * 3;
    lc[a][0] = l3[0]; lc[a][1] = l3[1]; lc[a][2] = l3[2];
  }

  // ---- Phase 1: Q projection (q = P @ Wq + bq), result bf16 in LDS ----
  f32x4 accq[4][4];
#pragma unroll
  for (int i = 0; i < 4; i++)
#pragma unroll
    for (int j = 0; j < 4; j++) accq[i][j] = fz;
  const int srow = tid >> 3, sc8 = (tid & 7) * 8;
  for (int kb = 0; kb < 8; kb++) {
    const float* src = protein + ((size_t)(b * 2048 + s0 + srow) * 512 + kb * 64 + sc8);
    float4 x0 = ((const float4*)src)[0];
    float4 x1 = ((const float4*)src)[1];
    short8 v;
    v[0] = f2bf(x0.x); v[1] = f2bf(x0.y); v[2] = f2bf(x0.z); v[3] = f2bf(x0.w);
    v[4] = f2bf(x1.x); v[5] = f2bf(x1.y); v[6] = f2bf(x1.z); v[7] = f2bf(x1.w);
    *(short8*)(ub + srow * 128 + SWZ(srow, sc8 * 2)) = v;
    __syncthreads();
#pragma unroll
    for (int kk = 0; kk < 64; kk += 32) {
      short8 af[4];
#pragma unroll
      for (int mt = 0; mt < 4; mt++) {
        int row = mt * 16 + c;
        af[mt] = *(const short8*)(ub + row * 128 + SWZ(row, kk * 2 + g * 16));
      }
#pragma unroll
      for (int nt = 0; nt < 4; nt++) {
        short8 bf = *(const short8*)(WqT + (size_t)(w * 64 + nt * 16 + c) * 512 +
                                     kb * 64 + kk + g * 8);
#pragma unroll
        for (int mt = 0; mt < 4; mt++)
          accq[mt][nt] = MFMA16(af[mt], bf, accq[mt][nt]);
      }
    }
    __syncthreads();
  }
#pragma unroll
  for (int nt = 0; nt < 4; nt++) {
    int col = w * 64 + nt * 16 + c;
    float bqv = bq[col];
#pragma unroll
    for (int mt = 0; mt < 4; mt++)
#pragma unroll
      for (int r = 0; r < 4; r++) {
        int row = mt * 16 + g * 4 + r;
        *(short*)(qb + row * 1024 + SWZ(row, col * 2)) = f2bf(accq[mt][nt][r] + bqv);
      }
  }
  __syncthreads();

  // ---- Phase 2: per-head scores + softmax + PV ----
  const int aidx = w * 16 + c;  // this wave's a-column slice: [w*16, w*16+16)
  const float lcx = lc[aidx][0], lcy = lc[aidx][1], lcz = lc[aidx][2];
  for (int h = 0; h < 8; h++) {
    const float wdh = Wdp[h];
    const float bava = bav[((size_t)b * 128 + aidx) * 8 + h];
    f32x4 accs[4];
#pragma unroll
    for (int mt = 0; mt < 4; mt++) accs[mt] = fz;
#pragma unroll
    for (int kk = 0; kk < 64; kk += 32) {
      short8 bf = *(const short8*)(kbuf + ((size_t)(b * 8 + h) * 128 + aidx) * 64 +
                                   kk + g * 8);
#pragma unroll
      for (int mt = 0; mt < 4; mt++) {
        int row = mt * 16 + c;
        short8 af = *(const short8*)(qb + row * 1024 + SWZ(row, h * 128 + kk * 2 + g * 16));
        accs[mt] = MFMA16(af, bf, accs[mt]);
      }
    }
    // bias (scale, distance, atom/mask) + per-wave row-max over 16 a-cols
#pragma unroll
    for (int mt = 0; mt < 4; mt++)
#pragma unroll
      for (int r = 0; r < 4; r++) {
        int row = mt * 16 + g * 4 + r;
        float dx = pc[row][0] - lcx, dy = pc[row][1] - lcy, dz = pc[row][2] - lcz;
        float dist = sqrtf(dx * dx + dy * dy + dz * dz);
        float scv = accs[mt][r] * 0.125f + dist * wdh + bava;
        accs[mt][r] = scv;
        float m = scv;
        m = fmaxf(m, __shfl_xor(m, 1));
        m = fmaxf(m, __shfl_xor(m, 2));
        m = fmaxf(m, __shfl_xor(m, 4));
        m = fmaxf(m, __shfl_xor(m, 8));
        if (c == 0) red[row][w] = m;
      }
    __syncthreads();
    if (tid < 64) {
      float m = red[tid][0];
#pragma unroll
      for (int j = 1; j < 8; j++) m = fmaxf(m, red[tid][j]);
      rmaxl[tid] = m;
    }
    __syncthreads();
    // exp, write P (bf16) into scratch, partial row-sums
#pragma unroll
    for (int mt = 0; mt < 4; mt++)
#pragma unroll
      for (int r = 0; r < 4; r++) {
        int row = mt * 16 + g * 4 + r;
        float p = __expf(accs[mt][r] - rmaxl[row]);
        *(short*)(ub + row * 256 + SWZ(row, aidx * 2)) = f2bf(p);
        float s = p;
        s += __shfl_xor(s, 1);
        s += __shfl_xor(s, 2);
        s += __shfl_xor(s, 4);
        s += __shfl_xor(s, 8);
        if (c == 0) red[row][w] = s;
      }
    __syncthreads();
    if (tid < 64) {
      float s = 0.f;
#pragma unroll
      for (int j = 0; j < 8; j++) s += red[tid][j];
      rinvl[tid] = 1.0f / s;
    }
    __syncthreads();
    // PV: out_h[64 s x 64 d]; wave -> (mtp = w>>1, 2 n-tiles at (w&1)*2)
    const int mtp = w >> 1, nt0 = (w & 1) * 2;
    f32x4 accv[2] = {fz, fz};
#pragma unroll
    for (int kc = 0; kc < 4; kc++) {
      int prow = mtp * 16 + c;
      short8 af = *(const short8*)(ub + prow * 256 + SWZ(prow, kc * 64 + g * 16));
#pragma unroll
      for (int j = 0; j < 2; j++) {
        short8 bf = *(const short8*)(vtbuf + ((size_t)(b * 8 + h) * 64 +
                                              (nt0 + j) * 16 + c) * 128 +
                                     kc * 32 + g * 8);
        accv[j] = MFMA16(af, bf, accv[j]);
      }
    }
#pragma unroll
    for (int r = 0; r < 4; r++) {
      int row = mtp * 16 + g * 4 + r;
      float riv = rinvl[row];
#pragma unroll
      for (int j = 0; j < 2; j++) {
        int col = h * 64 + (nt0 + j) * 16 + c;
        *(short*)(aob + row * 1024 + SWZ(row, col * 2)) = f2bf(accv[j][r] * riv);
      }
    }
  }
  __syncthreads();

  // ---- Phase 3: output projection (out = ao @ Wo + bo), fp32 store ----
  f32x4 acco[4][4];
#pragma unroll
  for (int i = 0; i < 4; i++)
#pragma unroll
    for (int j = 0; j < 4; j++) acco[i][j] = fz;
  for (int kc = 0; kc < 16; kc++) {
    short8 af[4];
#pragma unroll
    for (int mt = 0; mt < 4; mt++) {
      int row = mt * 16 + c;
      af[mt] = *(const short8*)(aob + row * 1024 + SWZ(row, kc * 64 + g * 16));
    }
#pragma unroll
    for (int nt = 0; nt < 4; nt++) {
      short8 bf = *(const short8*)(WoT + (size_t)(w * 64 + nt * 16 + c) * 512 +
                                   kc * 32 + g * 8);
#pragma unroll
      for (int mt = 0; mt < 4; mt++)
        acco[mt][nt] = MFMA16(af[mt], bf, acco[mt][nt]);
    }
  }
#pragma unroll
  for (int nt = 0; nt < 4; nt++) {
    int col = w * 64 + nt * 16 + c;
    float bov = bo[col];
#pragma unroll
    for (int mt = 0; mt < 4; mt++)
#pragma unroll
      for (int r = 0; r < 4; r++) {
        int row = mt * 16 + g * 4 + r;
        out[((size_t)b * 2048 + s0 + row) * 512 + col] = acco[mt][nt][r] + bov;
      }
  }
}

// ---------------------------------------------------------------------------
extern "C" void kernel_launch(void* const* d_in, const int* in_sizes, int n_in,
                              void* d_out, int out_size, void* d_ws, size_t ws_size,
                              hipStream_t stream) {
  const float* protein = (const float*)d_in[0];
  const float* ligand  = (const float*)d_in[1];
  const float* pcoord  = (const float*)d_in[2];
  const float* lcoord  = (const float*)d_in[3];
  const int*   atypes  = (const int*)d_in[4];
  const int*   lmask   = (const int*)d_in[5];
  const float* Wq = (const float*)d_in[6];
  const float* bq = (const float*)d_in[7];
  const float* Wk = (const float*)d_in[8];
  const float* bk = (const float*)d_in[9];
  const float* Wv = (const float*)d_in[10];
  const float* bv = (const float*)d_in[11];
  const float* Wo = (const float*)d_in[12];
  const float* bo = (const float*)d_in[13];
  const float* Wd = (const float*)d_in[14];
  const float* bd = (const float*)d_in[15];
  const float* aemb = (const float*)d_in[16];

  char* ws = (char*)d_ws;
  const size_t WSLOT = (size_t)512 * 512 * 2;  // 512 KB per bf16 weight
  unsigned short* WqT = (unsigned short*)(ws + 0 * WSLOT);
  unsigned short* WkT = (unsigned short*)(ws + 1 * WSLOT);
  unsigned short* WvT = (unsigned short*)(ws + 2 * WSLOT);
  unsigned short* WoT = (unsigned short*)(ws + 3 * WSLOT);
  unsigned short* kbuf  = (unsigned short*)(ws + 4 * WSLOT);               // 2 MB
  unsigned short* vtbuf = (unsigned short*)(ws + 4 * WSLOT + (2u << 20)); // 2 MB
  float* bav = (float*)(ws + 4 * WSLOT + (4u << 20));                      // 64 KB

  wtrans_kernel<<<dim3(8, 8, 4), 256, 0, stream>>>(Wq, Wk, Wv, Wo, WqT);
  bav_kernel<<<8, 256, 0, stream>>>(atypes, lmask, bd, aemb, bav);
  kvproj_kernel<<<dim3(2, 16), 512, 0, stream>>>(ligand, WkT, WvT, bk, bv, kbuf, vtbuf);
  fused_kernel<<<dim3(32, 16), 512, 0, stream>>>(protein, pcoord, lcoord, Wd, bq, bo,
                                                 WqT, WoT, kbuf, vtbuf, bav,
                                                 (float*)d_out);
}

// Round 2
// 290.141 us; speedup vs baseline: 1.4456x; 1.4456x over previous
//
#include <hip/hip_runtime.h>
#include <hip/hip_bf16.h>

// LigandCrossAttention fused bf16-MFMA implementation for gfx950, v2.
// B=16, S=2048, A=128, D_MODEL=512, H=8, Dh=64.
// Structure: prep (weight transpose + atom bias) -> kvproj -> fused.
// fused: wave==head in attention phase; swapped-operand QK^T so softmax is
// lane-local (2 shfl_xor only); P stays in registers (pi-permuted vtbuf);
// 3 barriers total per block.

typedef __attribute__((ext_vector_type(8))) short short8;   // 8 x bf16 bits
typedef __attribute__((ext_vector_type(4))) float f32x4;
typedef __attribute__((ext_vector_type(4))) unsigned int u32x4;

#define MFMA16(a, b, c) __builtin_amdgcn_mfma_f32_16x16x32_bf16((a), (b), (c), 0, 0, 0)
#define LOG2E 1.44269504088896340736f

__device__ __forceinline__ unsigned int cvtpk(float lo, float hi) {
  unsigned int r;
  asm("v_cvt_pk_bf16_f32 %0, %1, %2" : "=v"(r) : "v"(lo), "v"(hi));
  return r;
}
__device__ __forceinline__ short f2bf1(float f) {  // single fp32 -> bf16 (RNE)
  return (short)(cvtpk(f, f) & 0xffffu);
}
__device__ __forceinline__ short f2bf(float f) {   // manual RNE (prep path)
  unsigned int u = __float_as_uint(f);
  u += 0x7FFFu + ((u >> 16) & 1u);
  return (short)(u >> 16);
}
__device__ __forceinline__ float bexp2(float x) {
  float r;
  asm("v_exp_f32 %0, %1" : "=v"(r) : "v"(x));
  return r;
}

// ---------------------------------------------------------------------------
// Kernel 1: prep = weight transpose (fp32 [512][512] -> bf16 [n][k], 4 weights)
//           + atom/mask bias table bav2[b][h][a] (pre-scaled by log2e).
// grid (8,8,5): z<4 -> transpose slices; z==4 -> bav.
// ---------------------------------------------------------------------------
__global__ __launch_bounds__(256)
void prep_kernel(const float* __restrict__ Wq, const float* __restrict__ Wk,
                 const float* __restrict__ Wv, const float* __restrict__ Wo,
                 unsigned short* __restrict__ dst,
                 const int* __restrict__ types, const int* __restrict__ mask,
                 const float* __restrict__ bd, const float* __restrict__ aemb,
                 float* __restrict__ bav2) {
  if (blockIdx.z == 4) {
    if (blockIdx.y != 0) return;
    int t = blockIdx.x * 256 + threadIdx.x;  // 0..2047 = b*128 + a
    int msk = mask[t];
    int tp = types[t];
    int b = t >> 7, a = t & 127;
#pragma unroll
    for (int h = 0; h < 8; h++)
      bav2[((size_t)b * 8 + h) * 128 + a] =
          msk ? (aemb[tp * 8 + h] + bd[h]) * LOG2E : -1e30f;
    return;
  }
  __shared__ float t[64][65];
  const int wsel = blockIdx.z;
  const float* src = (wsel == 0) ? Wq : (wsel == 1) ? Wk : (wsel == 2) ? Wv : Wo;
  unsigned short* d = dst + (size_t)wsel * 512 * 512;
  const int k0 = blockIdx.x * 64, n0 = blockIdx.y * 64;
  const int c = threadIdx.x & 63, r4 = threadIdx.x >> 6;
#pragma unroll
  for (int i = 0; i < 16; i++) {
    int row = i * 4 + r4;
    t[row][c] = src[(size_t)(k0 + row) * 512 + n0 + c];
  }
  __syncthreads();
#pragma unroll
  for (int i = 0; i < 16; i++) {
    int row = i * 4 + r4;
    d[(size_t)(n0 + row) * 512 + k0 + c] = (unsigned short)f2bf(t[c][row]);
  }
}

// ---------------------------------------------------------------------------
// Kernel 2: K/V projection. grid=(2 [k|v], 16 [b]), 512 thr.
// K -> kbuf[b][h][a][d] bf16 (natural) ;
// V -> vtbuf[b][h][d][pos] bf16 with pi-permuted a-order:
//      pos = (a>>5)*32 + g*8 + hi*4 + r  for a = mt*16 + g*4 + r, hi = mt&1.
// ---------------------------------------------------------------------------
__global__ __launch_bounds__(512)
void kvproj_kernel(const float* __restrict__ ligand,
                   const unsigned short* __restrict__ WkT,
                   const unsigned short* __restrict__ WvT,
                   const float* __restrict__ bk, const float* __restrict__ bv,
                   unsigned short* __restrict__ kbuf,
                   unsigned short* __restrict__ vtbuf) {
  __shared__ short st[128 * 64];
  char* sb = (char*)st;
  const int kv = blockIdx.x, b = blockIdx.y;
  const unsigned short* WT = kv ? WvT : WkT;
  const float* bias = kv ? bv : bk;
  const int tid = threadIdx.x, lane = tid & 63, w = tid >> 6;
  const int c = lane & 15, g = lane >> 4;
  const f32x4 fz = {0.f, 0.f, 0.f, 0.f};
  f32x4 acc[8][4];
#pragma unroll
  for (int i = 0; i < 8; i++)
#pragma unroll
    for (int j = 0; j < 4; j++) acc[i][j] = fz;
  const int srow = tid >> 2, sq = tid & 3;
  for (int kb = 0; kb < 8; kb++) {
    const float* src = ligand + ((size_t)(b * 128 + srow) * 512 + kb * 64 + sq * 16);
    float4 x0 = ((const float4*)src)[0];
    float4 x1 = ((const float4*)src)[1];
    float4 x2 = ((const float4*)src)[2];
    float4 x3 = ((const float4*)src)[3];
    short8 v0, v1;
    v0[0] = f2bf(x0.x); v0[1] = f2bf(x0.y); v0[2] = f2bf(x0.z); v0[3] = f2bf(x0.w);
    v0[4] = f2bf(x1.x); v0[5] = f2bf(x1.y); v0[6] = f2bf(x1.z); v0[7] = f2bf(x1.w);
    v1[0] = f2bf(x2.x); v1[1] = f2bf(x2.y); v1[2] = f2bf(x2.z); v1[3] = f2bf(x2.w);
    v1[4] = f2bf(x3.x); v1[5] = f2bf(x3.y); v1[6] = f2bf(x3.z); v1[7] = f2bf(x3.w);
    *(short8*)(sb + srow * 128 + ((sq * 32) ^ ((srow & 7) << 4))) = v0;
    *(short8*)(sb + srow * 128 + ((sq * 32 + 16) ^ ((srow & 7) << 4))) = v1;
    __syncthreads();
#pragma unroll
    for (int kk = 0; kk < 64; kk += 32) {
      short8 af[8];
#pragma unroll
      for (int mt = 0; mt < 8; mt++) {
        int row = mt * 16 + c;
        af[mt] = *(const short8*)(sb + row * 128 + ((kk * 2 + g * 16) ^ ((row & 7) << 4)));
      }
#pragma unroll
      for (int nt = 0; nt < 4; nt++) {
        short8 bf = *(const short8*)(WT + (size_t)(w * 64 + nt * 16 + c) * 512 +
                                     kb * 64 + kk + g * 8);
#pragma unroll
        for (int mt = 0; mt < 8; mt++)
          acc[mt][nt] = MFMA16(af[mt], bf, acc[mt][nt]);
      }
    }
    __syncthreads();
  }
#pragma unroll
  for (int nt = 0; nt < 4; nt++) {
    int col = w * 64 + nt * 16 + c;
    float bs = bias[col];
    int h = col >> 6, dd = col & 63;
#pragma unroll
    for (int mt = 0; mt < 8; mt++)
#pragma unroll
      for (int r = 0; r < 4; r++) {
        int a = mt * 16 + g * 4 + r;  // D-layout: row = 4*(lane>>4)+reg
        unsigned short us = (unsigned short)f2bf(acc[mt][nt][r] + bs);
        if (!kv) {
          kbuf[((size_t)(b * 8 + h) * 128 + a) * 64 + dd] = us;
        } else {
          int pos = (mt >> 1) * 32 + g * 8 + (mt & 1) * 4 + r;  // pi-permuted
          vtbuf[((size_t)(b * 8 + h) * 64 + dd) * 128 + pos] = us;
        }
      }
  }
}

// ---------------------------------------------------------------------------
// Kernel 3: fused Q-proj + attention (wave==head) + O-proj.
// grid=(32 s-tiles, 16 b), 512 thr. 3 barriers total.
// qao region (64 KB) is used as: protein-stage [64][512] -> q [16][64][32]
// -> ao [16][64][32] (frag-ready, slot-swizzled).
// ---------------------------------------------------------------------------
__global__ __launch_bounds__(512, 2)
void fused_kernel(const float* __restrict__ protein, const float* __restrict__ pcoord,
                  const float* __restrict__ lcoord, const float* __restrict__ Wdp,
                  const float* __restrict__ bq, const float* __restrict__ bo,
                  const unsigned short* __restrict__ WqT,
                  const unsigned short* __restrict__ WoT,
                  const unsigned short* __restrict__ kbuf,
                  const unsigned short* __restrict__ vtbuf,
                  const float* __restrict__ bav2, float* __restrict__ out) {
  __shared__ short8 qao_v[4096];              // 64 KB
  __shared__ __align__(16) float distl[8192]; // 32 KB
  char* qb = (char*)qao_v;

  const int b = blockIdx.y, s0 = blockIdx.x * 64;
  const int tid = threadIdx.x, lane = tid & 63, w = tid >> 6;
  const int c = lane & 15, g = lane >> 4;
  const f32x4 fz = {0.f, 0.f, 0.f, 0.f};

  // ---- Stage A: protein tile [64][512] fp32 -> bf16 LDS, row-XOR-swizzled ----
#pragma unroll
  for (int i = 0; i < 8; i++) {
    int idx = i * 512 + tid;  // short8 index within the 64x512 tile
    const float* src = protein + (size_t)(b * 2048 + s0) * 512 + idx * 8;
    float4 x0 = ((const float4*)src)[0];
    float4 x1 = ((const float4*)src)[1];
    uint4 v;
    v.x = cvtpk(x0.x, x0.y); v.y = cvtpk(x0.z, x0.w);
    v.z = cvtpk(x1.x, x1.y); v.w = cvtpk(x1.z, x1.w);
    int row = idx >> 6, sl = idx & 63;
    *(uint4*)(qb + row * 1024 + ((sl * 16) ^ ((row & 7) << 4))) = v;
  }
  // ---- Stage B: dist[s][a] fp32 LDS (computed ONCE per block), a-swizzled ----
  {
    int s = tid >> 3, a0 = (tid & 7) * 16;
    const float* p3 = pcoord + (size_t)(b * 2048 + s0 + s) * 3;
    float px = p3[0], py = p3[1], pz = p3[2];
#pragma unroll
    for (int ii = 0; ii < 4; ii++) {
      f32x4 d4;
#pragma unroll
      for (int r = 0; r < 4; r++) {
        int a = a0 + ii * 4 + r;
        const float* l3 = lcoord + (size_t)(b * 128 + a) * 3;
        float dx = px - l3[0], dy = py - l3[1], dz = pz - l3[2];
        d4[r] = sqrtf(dx * dx + dy * dy + dz * dz);
      }
      *(f32x4*)(distl + s * 128 + ((a0 + ii * 4) ^ ((s & 7) << 2))) = d4;
    }
  }
  __syncthreads();  // barrier 1

  // ---- Phase 1: Q-proj (q = P @ Wq + bq), 256 MFMAs/wave, no inner barriers ----
  f32x4 accq[4][4];
#pragma unroll
  for (int i = 0; i < 4; i++)
#pragma unroll
    for (int j = 0; j < 4; j++) accq[i][j] = fz;
  for (int kp = 0; kp < 16; kp++) {
    short8 bfr[4], afr[4];
#pragma unroll
    for (int nt = 0; nt < 4; nt++)
      bfr[nt] = *(const short8*)(WqT + (size_t)(w * 64 + nt * 16 + c) * 512 +
                                 kp * 32 + g * 8);
#pragma unroll
    for (int mt = 0; mt < 4; mt++) {
      int row = mt * 16 + c;
      afr[mt] = *(const short8*)(qb + row * 1024 +
                                 ((kp * 64 + g * 16) ^ ((row & 7) << 4)));
    }
#pragma unroll
    for (int nt = 0; nt < 4; nt++)
#pragma unroll
      for (int mt = 0; mt < 4; mt++)
        accq[mt][nt] = MFMA16(afr[mt], bfr[nt], accq[mt][nt]);
  }
  __syncthreads();  // barrier 2: protein reads done; q may overwrite region

  // q write: n = w*64+nt*16+c -> chunk = 2w + (nt>>1), slot p = (nt&1)*16+c,
  // row s = mt*16+g*4+r; slot XOR-swizzled by s.
#pragma unroll
  for (int nt = 0; nt < 4; nt++) {
    int n = w * 64 + nt * 16 + c;
    float bqv = bq[n];
    int chunk = w * 2 + (nt >> 1);
    int p = (nt & 1) * 16 + c;
#pragma unroll
    for (int mt = 0; mt < 4; mt++)
#pragma unroll
      for (int r = 0; r < 4; r++) {
        int s = mt * 16 + g * 4 + r;
        int slot = p ^ (((s & 1) << 3) | (((s >> 2) & 1) << 4));
        *(short*)(qb + (chunk * 64 + s) * 64 + slot * 2) =
            f2bf1(accq[mt][nt][r] + bqv);
      }
  }
  // No barrier: each wave reads back only its own q slice (chunks 2w, 2w+1).

  // ---- Phase 2: attention, wave == head (h = w). Zero barriers. ----
  const int h = w;
  const float wdh2 = Wdp[h] * LOG2E;
  const float c1 = 0.125f * LOG2E;  // 1/sqrt(64) * log2(e)
  const unsigned short* kb_h = kbuf + (size_t)(b * 8 + h) * 128 * 64;
  const unsigned short* vt_h = vtbuf + (size_t)(b * 8 + h) * 64 * 128;
  const float* bav_h = bav2 + (size_t)(b * 8 + h) * 128;

  short8 qf[4][2];
#pragma unroll
  for (int st = 0; st < 4; st++) {
    int s = st * 16 + c;
    int sx = ((s & 1) << 3) | (((s >> 2) & 1) << 4);
#pragma unroll
    for (int kq = 0; kq < 2; kq++)
      qf[st][kq] = *(const short8*)(qb + ((h * 2 + kq) * 64 + s) * 64 +
                                    ((g * 8) ^ sx) * 2);
  }
  // S^T = mfma(K, Q): D col = s (lane&15), rows = a  -> softmax lane-local.
  f32x4 sc[8][4];
#pragma unroll
  for (int i = 0; i < 8; i++)
#pragma unroll
    for (int j = 0; j < 4; j++) sc[i][j] = fz;
#pragma unroll
  for (int at = 0; at < 8; at++) {
    const unsigned short* kr = kb_h + (at * 16 + c) * 64;
    short8 kf0 = *(const short8*)(kr + g * 8);
    short8 kf1 = *(const short8*)(kr + 32 + g * 8);
#pragma unroll
    for (int st = 0; st < 4; st++) sc[at][st] = MFMA16(kf0, qf[st][0], sc[at][st]);
#pragma unroll
    for (int st = 0; st < 4; st++) sc[at][st] = MFMA16(kf1, qf[st][1], sc[at][st]);
  }
  // bias (scale, dist, atom/mask — all pre-scaled to log2 domain) + row max
  float mx[4] = {-3e38f, -3e38f, -3e38f, -3e38f};
#pragma unroll
  for (int at = 0; at < 8; at++) {
    f32x4 bv = *(const f32x4*)(bav_h + at * 16 + g * 4);
#pragma unroll
    for (int st = 0; st < 4; st++) {
      int s = st * 16 + c;
      f32x4 dd = *(const f32x4*)(distl + s * 128 +
                                 ((at * 16 + g * 4) ^ ((s & 7) << 2)));
#pragma unroll
      for (int r = 0; r < 4; r++) {
        float v = fmaf(sc[at][st][r], c1, fmaf(dd[r], wdh2, bv[r]));
        sc[at][st][r] = v;
        mx[st] = fmaxf(mx[st], v);
      }
    }
  }
#pragma unroll
  for (int st = 0; st < 4; st++) {
    mx[st] = fmaxf(mx[st], __shfl_xor(mx[st], 16));
    mx[st] = fmaxf(mx[st], __shfl_xor(mx[st], 32));
  }
  float sum[4] = {0.f, 0.f, 0.f, 0.f};
#pragma unroll
  for (int at = 0; at < 8; at++)
#pragma unroll
    for (int st = 0; st < 4; st++)
#pragma unroll
      for (int r = 0; r < 4; r++) {
        float p = bexp2(sc[at][st][r] - mx[st]);
        sc[at][st][r] = p;
        sum[st] += p;
      }
#pragma unroll
  for (int st = 0; st < 4; st++) {
    sum[st] += __shfl_xor(sum[st], 16);
    sum[st] += __shfl_xor(sum[st], 32);
  }
  float rinv[4];
#pragma unroll
  for (int st = 0; st < 4; st++) rinv[st] = 1.f / sum[st];

  // PV: out^T = mfma(V^T, P^T); P stays in registers (pi-permuted B-frags).
  f32x4 pv[4][4];
#pragma unroll
  for (int i = 0; i < 4; i++)
#pragma unroll
    for (int j = 0; j < 4; j++) pv[i][j] = fz;
#pragma unroll
  for (int ch = 0; ch < 4; ch++) {
    short8 pf[4];
#pragma unroll
    for (int st = 0; st < 4; st++) {
      u32x4 up;
      up[0] = cvtpk(sc[2 * ch][st][0], sc[2 * ch][st][1]);
      up[1] = cvtpk(sc[2 * ch][st][2], sc[2 * ch][st][3]);
      up[2] = cvtpk(sc[2 * ch + 1][st][0], sc[2 * ch + 1][st][1]);
      up[3] = cvtpk(sc[2 * ch + 1][st][2], sc[2 * ch + 1][st][3]);
      pf[st] = __builtin_bit_cast(short8, up);
    }
#pragma unroll
    for (int dt = 0; dt < 4; dt++) {
      short8 vf = *(const short8*)(vt_h + (dt * 16 + c) * 128 + ch * 32 + g * 8);
#pragma unroll
      for (int st = 0; st < 4; st++) pv[dt][st] = MFMA16(vf, pf[st], pv[dt][st]);
    }
  }
  // ao write (own chunks 2h, 2h+1), normalized, frag-ready + slot swizzle
#pragma unroll
  for (int dt = 0; dt < 4; dt++) {
    int chunk = h * 2 + (dt >> 1);
    int pbase = (dt & 1) * 16 + g * 4;
#pragma unroll
    for (int st = 0; st < 4; st++) {
      int s = st * 16 + c;
      int sx = ((s & 1) << 3) | (((s >> 2) & 1) << 4);
      uint2 wv;
      wv.x = cvtpk(pv[dt][st][0] * rinv[st], pv[dt][st][1] * rinv[st]);
      wv.y = cvtpk(pv[dt][st][2] * rinv[st], pv[dt][st][3] * rinv[st]);
      *(uint2*)(qb + (chunk * 64 + s) * 64 + (pbase ^ sx) * 2) = wv;
    }
  }
  __syncthreads();  // barrier 3: all ao slices visible

  // ---- Phase 3: O-proj out^T = mfma(Wo^T, ao^T), 256 MFMAs/wave ----
  f32x4 acco[4][4];
#pragma unroll
  for (int i = 0; i < 4; i++)
#pragma unroll
    for (int j = 0; j < 4; j++) acco[i][j] = fz;
  for (int kc = 0; kc < 16; kc++) {
    short8 af[4], bf[4];
#pragma unroll
    for (int nt = 0; nt < 4; nt++)
      af[nt] = *(const short8*)(WoT + (size_t)(w * 64 + nt * 16 + c) * 512 +
                                kc * 32 + g * 8);
#pragma unroll
    for (int st = 0; st < 4; st++) {
      int s = st * 16 + c;
      int sx = ((s & 1) << 3) | (((s >> 2) & 1) << 4);
      bf[st] = *(const short8*)(qb + (kc * 64 + s) * 64 + ((g * 8) ^ sx) * 2);
    }
#pragma unroll
    for (int nt = 0; nt < 4; nt++)
#pragma unroll
      for (int st = 0; st < 4; st++)
        acco[nt][st] = MFMA16(af[nt], bf[st], acco[nt][st]);
  }
  // store: out[b][s][no] fp32, float4 per (nt, st)
#pragma unroll
  for (int nt = 0; nt < 4; nt++) {
    f32x4 bo4 = *(const f32x4*)(bo + w * 64 + nt * 16 + g * 4);
#pragma unroll
    for (int st = 0; st < 4; st++) {
      int s = st * 16 + c;
      f32x4 o;
#pragma unroll
      for (int r = 0; r < 4; r++) o[r] = acco[nt][st][r] + bo4[r];
      *(f32x4*)(out + (size_t)(b * 2048 + s0 + s) * 512 + w * 64 + nt * 16 + g * 4) = o;
    }
  }
}

// ---------------------------------------------------------------------------
extern "C" void kernel_launch(void* const* d_in, const int* in_sizes, int n_in,
                              void* d_out, int out_size, void* d_ws, size_t ws_size,
                              hipStream_t stream) {
  const float* protein = (const float*)d_in[0];
  const float* ligand  = (const float*)d_in[1];
  const float* pcoord  = (const float*)d_in[2];
  const float* lcoord  = (const float*)d_in[3];
  const int*   atypes  = (const int*)d_in[4];
  const int*   lmask   = (const int*)d_in[5];
  const float* Wq = (const float*)d_in[6];
  const float* bq = (const float*)d_in[7];
  const float* Wk = (const float*)d_in[8];
  const float* bk = (const float*)d_in[9];
  const float* Wv = (const float*)d_in[10];
  const float* bv = (const float*)d_in[11];
  const float* Wo = (const float*)d_in[12];
  const float* bo = (const float*)d_in[13];
  const float* Wd = (const float*)d_in[14];
  const float* bd = (const float*)d_in[15];
  const float* aemb = (const float*)d_in[16];

  char* ws = (char*)d_ws;
  const size_t WSLOT = (size_t)512 * 512 * 2;  // 512 KB per bf16 weight
  unsigned short* WqT = (unsigned short*)(ws + 0 * WSLOT);
  unsigned short* WkT = (unsigned short*)(ws + 1 * WSLOT);
  unsigned short* WvT = (unsigned short*)(ws + 2 * WSLOT);
  unsigned short* WoT = (unsigned short*)(ws + 3 * WSLOT);
  unsigned short* kbuf  = (unsigned short*)(ws + 4 * WSLOT);                // 2 MB
  unsigned short* vtbuf = (unsigned short*)(ws + 4 * WSLOT + (2u << 20));   // 2 MB
  float* bav2 = (float*)(ws + 4 * WSLOT + (4u << 20));                      // 64 KB

  prep_kernel<<<dim3(8, 8, 5), 256, 0, stream>>>(Wq, Wk, Wv, Wo, WqT,
                                                 atypes, lmask, bd, aemb, bav2);
  kvproj_kernel<<<dim3(2, 16), 512, 0, stream>>>(ligand, WkT, WvT, bk, bv, kbuf, vtbuf);
  fused_kernel<<<dim3(32, 16), 512, 0, stream>>>(protein, pcoord, lcoord, Wd, bq, bo,
                                                 WqT, WoT, kbuf, vtbuf, bav2,
                                                 (float*)d_out);
}